// Round 8
// baseline (2266.679 us; speedup 1.0000x reference)
//
#include <hip/hip_runtime.h>
#include <hip/hip_fp16.h>
#include <math.h>

// MoE: 4 MLP experts + 4 FasterKAN experts, top-2 of 8, T=2048 H=1024 F=4096 F2=2048 G=8.
// Design: route+compact (4x FLOP cut); f16 MFMA (no fp32 MFMA on CDNA4); weights
// pre-transformed to per-k-step 8KB panels (transpose + bank-swizzle baked in) so
// GEMM B-staging is pure global_load_lds(16B); RSWAF basis + LayerNorm fused into
// A-staging (shared-exp trick); fused pair kernels (MLP||KAN) for pipe overlap;
// XCD-gathering block remap so row-blocks sharing a B-panel share an L2.

#define T_TOK 2048
#define H_DIM 1024
#define F_DIM 4096
#define F2_DIM 2048
#define CAP 2048
#define LN_EPS 1e-5f

typedef _Float16 f16x8 __attribute__((ext_vector_type(8)));
typedef float f32x4 __attribute__((ext_vector_type(4)));

__device__ __forceinline__ int swz16(int n){ return ((n>>1)&3) ^ ((n>>3)&1); }

__device__ __forceinline__ void gload16(const void* g, void* l){
  __builtin_amdgcn_global_load_lds(
      (const __attribute__((address_space(1))) unsigned int*)g,
      (__attribute__((address_space(3))) unsigned int*)l, 16, 0, 0);
}

__device__ __forceinline__ f16x8 f16zero(){
  f16x8 v;
#pragma unroll
  for (int i=0;i<8;i++) v[i] = (_Float16)0.f;
  return v;
}

// RSWAF: sech^2((u-g_j)/2) = 4 e_j/(1+e_j)^2, e_j = exp(u-g_j) = exp(u+1.2)*C_j.
// Shared exp: 1 exp + 8 rcp per 8 grid points (grid = -1.2 + 0.2j).
// Overflow-safe for |u| <= sqrt(dim) (LN bound): worst case qq^2=inf -> rcp=0 -> 0,
// which matches the true sech^2 limit at f16 resolution; NaN needs u>=87 (impossible).
__device__ __forceinline__ f16x8 basis8(float u){
  const float C[8] = {1.f,0.81873075f,0.67032005f,0.54881164f,
                      0.44932896f,0.36787944f,0.30119421f,0.24659696f};
  float e0 = __expf(u + 1.2f);
  f16x8 r;
#pragma unroll
  for (int j=0;j<8;j++){
    float e = e0*C[j];
    float qq = e + 1.f;
    r[j] = (_Float16)(4.f*e*__builtin_amdgcn_rcpf(qq*qq));
  }
  return r;
}

// ---------------- gate: fp32 logits, top-2, renorm weights; + x LN-stats ----------------
__global__ __launch_bounds__(256) void k_gate(const float* __restrict__ x,
    const float* __restrict__ gw, int* cnt, int* tok, float* wgt, float2* xstats)
{
  int t = blockIdx.x*4 + (threadIdx.x>>6);    // one wave per token
  int lane = threadIdx.x & 63;
  const float* xr = x + (size_t)t*H_DIM;
  float a[8] = {0.f,0.f,0.f,0.f,0.f,0.f,0.f,0.f};
  float s = 0.f, s2 = 0.f;
#pragma unroll
  for (int i=0;i<16;i++){
    int h = lane + 64*i;
    float xv = xr[h];
    s += xv; s2 += xv*xv;
    float4 g0 = *(const float4*)(gw + (size_t)h*8);
    float4 g1 = *(const float4*)(gw + (size_t)h*8 + 4);
    a[0]+=xv*g0.x; a[1]+=xv*g0.y; a[2]+=xv*g0.z; a[3]+=xv*g0.w;
    a[4]+=xv*g1.x; a[5]+=xv*g1.y; a[6]+=xv*g1.z; a[7]+=xv*g1.w;
  }
#pragma unroll
  for (int off=32; off; off>>=1){
#pragma unroll
    for (int i2=0;i2<8;i2++) a[i2] += __shfl_xor(a[i2], off);
    s += __shfl_xor(s, off); s2 += __shfl_xor(s2, off);
  }
  if (lane == 0){
    float mu = s*(1.f/H_DIM);
    float var = s2*(1.f/H_DIM) - mu*mu;
    xstats[t] = make_float2(mu, rsqrtf(var + LN_EPS));
    int e0 = 0; float m0v = a[0];
#pragma unroll
    for (int i2=1;i2<8;i2++) if (a[i2] > m0v){ m0v = a[i2]; e0 = i2; }   // ties -> lowest
    int e1 = 0; float m1v = -3.4e38f;
#pragma unroll
    for (int i2=0;i2<8;i2++) if (i2 != e0 && a[i2] > m1v){ m1v = a[i2]; e1 = i2; }
    float w0 = 1.f/(1.f + __expf(m1v - m0v));   // renorm top-2 softmax: denom cancels
    float w1 = 1.f - w0;
    int p = atomicAdd(&cnt[e0], 1);
    tok[(size_t)e0*CAP + p] = t; wgt[(size_t)e0*CAP + p] = w0;
    p = atomicAdd(&cnt[e1], 1);
    tok[(size_t)e1*CAP + p] = t; wgt[(size_t)e1*CAP + p] = w1;
  }
}

// ---------------- weight transform: f32 [K][N] -> f16 panels ----------------
// Panel layout: [panel p = n/128][kstep = k/32][row = n%128][slot 0..3][8 f16],
// with slot ^= swz16(n&15) baked in, so each GEMM k-step reads one contiguous
// 8KB chunk straight into LDS via global_load_lds and frag reads are ~2-way.
__global__ __launch_bounds__(256) void k_transform(
    const float* W1, const float* W2, const float* Wk0, const float* Wk1,
    _Float16* wt1, _Float16* wt2, _Float16* wk0, _Float16* wk1)
{
  __shared__ __align__(16) char lds[64*72];
  int i = blockIdx.x;
  const float* W; _Float16* Wt; int K, N, e, nb, kb;
  if (i < 256)      {           W=W1;  Wt=wt1; K=1024;  N=4096; e=i>>6; nb=i&63;          kb=0; }
  else if (i < 512) { int r=i-256;  W=W2;  Wt=wt2; K=4096;  N=1024; e=r>>6; nb=(r&63)&15;  kb=(r&63)>>4; }
  else if (i < 1536){ int r=i-512;  W=Wk0; Wt=wk0; K=8192;  N=2048; e=r>>8; nb=(r&255)&31; kb=(r&255)>>5; }
  else              { int r=i-1536; W=Wk1; Wt=wk1; K=16384; N=1024; e=r>>8; nb=(r&255)&15; kb=(r&255)>>4; }
  const float* We = W + (size_t)e*K*N;
  _Float16* Wte = Wt + (size_t)e*K*N;
  int n0 = nb*64;
  int t = threadIdx.x;
  int kb0 = kb*1024;
  for (int k0 = kb0; k0 < kb0+1024; k0 += 32){
    { // coalesced column reads: per-inst 64 consecutive n
      int n = t & 63, sgrp = t >> 6;
      float v[8];
#pragma unroll
      for (int j=0;j<8;j++) v[j] = We[(size_t)(k0+8*sgrp+j)*N + n0+n];
      union { _Float16 h[8]; uint2 u[2]; } cv;
#pragma unroll
      for (int j=0;j<8;j++) cv.h[j] = (_Float16)v[j];
      char* row = lds + n*72 + sgrp*16;
      *(uint2*)row     = cv.u[0];
      *(uint2*)(row+8) = cv.u[1];
    }
    __syncthreads();
    { // contiguous panel writes
      int n = t >> 2, sl = t & 3;
      char* row = lds + n*72 + sl*16;
      uint2 aa  = *(uint2*)row;
      uint2 bb2 = *(uint2*)(row+8);
      int gn = n0 + n;
      int p = gn >> 7, prow = gn & 127;
      int sp = sl ^ swz16(gn & 15);
      size_t dst = (((size_t)p*(K>>5) + (k0>>5))*128 + (size_t)prow)*32 + sp*8;
      float4 val;
      val.x = __uint_as_float(aa.x);  val.y = __uint_as_float(aa.y);
      val.z = __uint_as_float(bb2.x); val.w = __uint_as_float(bb2.y);
      *(float4*)(Wte + dst) = val;
    }
    __syncthreads();
  }
}

// ---------------- fused expert GEMM core (BM=BN=128, 4 waves, 16x16x32 f16) ----------
#define M_MLP1 0
#define M_KAN1 1
#define M_MLP2 2
#define M_KAN2 3

template<int MODE>
__device__ __forceinline__ void gemm_body(
    _Float16* Alds, _Float16* Blds,
    const float* fsrc, const _Float16* hsrc,
    const float2* xst, float* zst,
    const float* lng, const float* lnb,
    const _Float16* Wpan, const float* bias,
    const int* toke, const float* wgte,
    int nt, int e, int m0, int n0, int ks0, int ks1, bool addbias,
    float* outf, _Float16* outh)
{
  constexpr int KD = (MODE==M_MLP1)?H_DIM:(MODE==M_KAN1)?(H_DIM*8):(MODE==M_MLP2)?F_DIM:(F2_DIM*8);
  int tid = threadIdx.x, lane = tid&63, wid = tid>>6;
  int c15 = lane&15, q = lane>>4;
  int wm = (wid&1)*64, wn = (wid>>1)*64;

  f32x4 zero4 = {0.f,0.f,0.f,0.f};
  f32x4 acc[4][4];
#pragma unroll
  for (int a1=0;a1<4;a1++)
#pragma unroll
    for (int b1=0;b1<4;b1++) acc[a1][b1] = zero4;

  int aoff[4], boff[4];
#pragma unroll
  for (int ii=0;ii<4;ii++){
    aoff[ii] = (wm+ii*16+c15)*32 + ((q ^ swz16(c15))<<3);
    boff[ii] = (wn+ii*16+c15)*32 + ((q ^ swz16(c15))<<3);
  }

  // per-thread staged A row
  int sm = tid>>1;
  int gr = m0 + sm;
  bool valid = gr < nt;
  const float* arow = nullptr;
  const _Float16* hrow = nullptr;
  float mu = 0.f, rs = 0.f;
  if constexpr (MODE==M_MLP1 || MODE==M_KAN1){
    int tg = valid ? toke[gr] : 0;
    arow = fsrc + (size_t)tg*H_DIM;
    if constexpr (MODE==M_KAN1){
      float2 st = xst[tg]; mu = st.x; rs = st.y;
    }
  } else if constexpr (MODE==M_MLP2){
    hrow = hsrc + ((size_t)e*CAP + gr)*F_DIM;
  } else {
    arow = fsrc + ((size_t)e*CAP + gr)*F2_DIM;
    if (valid){
      float s1 = zst[2*((size_t)e*CAP+gr)];
      float s2 = zst[2*((size_t)e*CAP+gr)+1];
      float m = s1*(1.f/F2_DIM);
      float v = s2*(1.f/F2_DIM) - m*m;
      mu = m; rs = rsqrtf(v + LN_EPS);
    }
  }

  const char* pbase = (const char*)Wpan + (size_t)(n0>>7)*(KD>>5)*8192;
  char* bb = (char*)Blds;
  int lo16 = lane<<4;

  for (int ks = ks0; ks < ks1; ++ks){
    __syncthreads();
    // B: async 8KB panel chunk -> LDS (swizzle pre-baked in global layout)
    const char* bsrc = pbase + (size_t)ks*8192;
    gload16(bsrc + wid*1024 + lo16,        bb + wid*1024);
    gload16(bsrc + 4096 + wid*1024 + lo16, bb + 4096 + wid*1024);
    // A: reg-staged (gather+cvt / f16 / LN+basis on the fly), swizzled LDS writes
#pragma unroll
    for (int j=0;j<2;j++){
      int sidx = (tid&1) + 2*j;
      f16x8 av;
      if constexpr (MODE==M_MLP1){
        if (valid){
          const float* src = arow + ks*32 + 8*sidx;
          float4 f0 = *(const float4*)(src);
          float4 f1 = *(const float4*)(src+4);
          av[0]=(_Float16)f0.x; av[1]=(_Float16)f0.y; av[2]=(_Float16)f0.z; av[3]=(_Float16)f0.w;
          av[4]=(_Float16)f1.x; av[5]=(_Float16)f1.y; av[6]=(_Float16)f1.z; av[7]=(_Float16)f1.w;
        } else av = f16zero();
      } else if constexpr (MODE==M_MLP2){
        av = valid ? *(const f16x8*)(hrow + ks*32 + 8*sidx) : f16zero();
      } else {
        int h = (ks<<2) + sidx;
        float u = 0.f;
        if (valid) u = (arow[h] - mu)*rs*lng[h] + lnb[h];
        av = basis8(u);
      }
      *(f16x8*)(&Alds[sm*32 + ((sidx ^ swz16(sm & 15))<<3)]) = av;
    }
    __syncthreads();
    f16x8 af[4], bf[4];
#pragma unroll
    for (int ii=0;ii<4;ii++) af[ii] = *(const f16x8*)(&Alds[aoff[ii]]);
#pragma unroll
    for (int ii=0;ii<4;ii++) bf[ii] = *(const f16x8*)(&Blds[boff[ii]]);
#pragma unroll
    for (int ii=0;ii<4;ii++)
#pragma unroll
      for (int jj=0;jj<4;jj++)
        acc[ii][jj] = __builtin_amdgcn_mfma_f32_16x16x32_f16(af[ii], bf[jj], acc[ii][jj], 0,0,0);
  }

  // epilogue; C/D: col = lane&15, row = (lane>>4)*4 + reg
#pragma unroll
  for (int ai=0;ai<4;ai++){
#pragma unroll
    for (int r=0;r<4;r++){
      int mrow = m0 + wm + ai*16 + q*4 + r;
      bool rv = mrow < nt;
      float rsum = 0.f, rsq = 0.f;
      int tg = 0; float w = 0.f;
      if constexpr (MODE==M_MLP2 || MODE==M_KAN2){
        if (rv){ tg = toke[mrow]; w = wgte[mrow]; }
      }
#pragma unroll
      for (int bi=0;bi<4;bi++){
        int n = n0 + wn + bi*16 + c15;
        float v = acc[ai][bi][r];
        if constexpr (MODE==M_MLP1){
          v += bias[n];
          v = v*0.5f*(1.f + erff(v*0.70710678118654752f));   // exact GELU
          if (rv) outh[((size_t)e*CAP + mrow)*F_DIM + n] = (_Float16)v;
        } else if constexpr (MODE==M_KAN1){
          v += bias[n];
          if (rv){ outf[((size_t)e*CAP + mrow)*F2_DIM + n] = v; rsum += v; rsq += v*v; }
        } else {
          if (addbias) v += bias[n];
          if (rv) atomicAdd(&outf[(size_t)tg*H_DIM + n], w*v);
        }
      }
      if constexpr (MODE==M_KAN1){   // z row-stats for fused LN1 (partial over our 64 cols)
#pragma unroll
        for (int mk=1; mk<16; mk<<=1){
          rsum += __shfl_xor(rsum, mk);
          rsq  += __shfl_xor(rsq,  mk);
        }
        if (rv && c15==0){
          atomicAdd(&zst[2*((size_t)e*CAP+mrow)],   rsum);
          atomicAdd(&zst[2*((size_t)e*CAP+mrow)+1], rsq);
        }
      }
    }
  }
}

// ---------------- pair kernels (XCD-gathering remap: row-blocks share L2) -------------
__global__ __launch_bounds__(256) void k_pair1(
    const float* x, const _Float16* wt1, const float* mlpB1,
    const _Float16* wk0, const float* kanB0,
    const float2* xstats, const float* lng0, const float* lnb0,
    const int* cnt, const int* tok, const float* wgt,
    _Float16* h1, float* zbuf, float* zstats)
{
  __shared__ __align__(16) _Float16 Alds[128*32];
  __shared__ __align__(16) _Float16 Blds[128*32];
  int P = blockIdx.x;
  int L = (P & 7)*384 + (P >> 3);            // 3072 blocks / 8 XCDs
  if (L < 2048){                              // MLP1: e4 x cb32 x rb16
    int rb = L & 15, cb = (L>>4)&31, e = L>>9;
    int nt = cnt[e]; int m0 = rb*128;
    if (m0 >= nt) return;
    gemm_body<M_MLP1>(Alds, Blds, x, nullptr, nullptr, nullptr, nullptr, nullptr,
        wt1 + (size_t)e*F_DIM*H_DIM, mlpB1 + (size_t)e*F_DIM,
        tok + (size_t)e*CAP, wgt + (size_t)e*CAP,
        nt, e, m0, cb*128, 0, H_DIM/32, true, nullptr, h1);
  } else {                                    // KAN1: e4 x cb16 x rb16
    int L2 = L - 2048;
    int rb = L2 & 15, cb = (L2>>4)&15, e = L2>>8;
    int nt = cnt[4+e]; int m0 = rb*128;
    if (m0 >= nt) return;
    gemm_body<M_KAN1>(Alds, Blds, x, nullptr, xstats, zstats,
        lng0 + (size_t)e*H_DIM, lnb0 + (size_t)e*H_DIM,
        wk0 + (size_t)e*F2_DIM*(H_DIM*8), kanB0 + (size_t)e*F2_DIM,
        tok + (size_t)(4+e)*CAP, wgt + (size_t)(4+e)*CAP,
        nt, e, m0, cb*128, 0, (H_DIM*8)/32, true, zbuf, nullptr);
  }
}

__global__ __launch_bounds__(256) void k_pair2(
    const _Float16* h1, const _Float16* wt2, const float* mlpB2,
    const float* zbuf, const _Float16* wk1, const float* kanB1,
    float* zstats, const float* lng1, const float* lnb1,
    const int* cnt, const int* tok, const float* wgt, float* out)
{
  __shared__ __align__(16) _Float16 Alds[128*32];
  __shared__ __align__(16) _Float16 Blds[128*32];
  int P = blockIdx.x;
  int L = (P & 7)*256 + (P >> 3);            // 2048 blocks / 8 XCDs
  if (L < 1024){                              // MLP2: e4 x cb8 x s2 x rb16, split-K
    int rb = L&15, s = (L>>4)&1, cb = (L>>5)&7, e = L>>8;
    int nt = cnt[e]; int m0 = rb*128;
    if (m0 >= nt) return;
    gemm_body<M_MLP2>(Alds, Blds, nullptr, h1, nullptr, nullptr, nullptr, nullptr,
        wt2 + (size_t)e*H_DIM*F_DIM, mlpB2 + (size_t)e*H_DIM,
        tok + (size_t)e*CAP, wgt + (size_t)e*CAP,
        nt, e, m0, cb*128, s*64, s*64+64, s==0, out, nullptr);
  } else {                                    // KAN2
    int L2 = L-1024;
    int rb = L2&15, s = (L2>>4)&1, cb = (L2>>5)&7, e = L2>>8;
    int nt = cnt[4+e]; int m0 = rb*128;
    if (m0 >= nt) return;
    gemm_body<M_KAN2>(Alds, Blds, zbuf, nullptr, nullptr, zstats,
        lng1 + (size_t)e*F2_DIM, lnb1 + (size_t)e*F2_DIM,
        wk1 + (size_t)e*H_DIM*(F2_DIM*8), kanB1 + (size_t)e*H_DIM,
        tok + (size_t)(4+e)*CAP, wgt + (size_t)(4+e)*CAP,
        nt, e, m0, cb*128, s*256, s*256+256, s==0, out, nullptr);
  }
}

// ---------------- launch ----------------
extern "C" void kernel_launch(void* const* d_in, const int* in_sizes, int n_in,
                              void* d_out, int out_size, void* d_ws, size_t ws_size,
                              hipStream_t stream)
{
  const float* x     = (const float*)d_in[0];
  const float* gateW = (const float*)d_in[1];
  const float* mlpW1 = (const float*)d_in[2];
  const float* mlpB1 = (const float*)d_in[3];
  const float* mlpW2 = (const float*)d_in[4];
  const float* mlpB2 = (const float*)d_in[5];
  const float* lng0  = (const float*)d_in[6];
  const float* lnb0  = (const float*)d_in[7];
  const float* kanW0 = (const float*)d_in[8];
  const float* kanB0 = (const float*)d_in[9];
  const float* lng1  = (const float*)d_in[10];
  const float* lnb1  = (const float*)d_in[11];
  const float* kanW1 = (const float*)d_in[12];
  const float* kanB1 = (const float*)d_in[13];
  float* out = (float*)d_out;
  char* ws = (char*)d_ws;

  size_t off = 0;
  int* cnt      = (int*)(ws);             off  = 256;
  int* tok      = (int*)(ws + off);       off += (size_t)8*CAP*4;
  float* wgt    = (float*)(ws + off);     off += (size_t)8*CAP*4;
  float2* xst   = (float2*)(ws + off);    off += (size_t)T_TOK*8;
  float* zstats = (float*)(ws + off);     off += (size_t)4*CAP*2*4;
  _Float16* h1  = (_Float16*)(ws + off);  off += (size_t)4*CAP*F_DIM*2;
  float* zbuf   = (float*)(ws + off);     off += (size_t)4*CAP*F2_DIM*4;
  _Float16* wt1 = (_Float16*)(ws + off);  off += (size_t)4*F_DIM*H_DIM*2;
  _Float16* wt2 = (_Float16*)(ws + off);  off += (size_t)4*H_DIM*F_DIM*2;
  _Float16* wk0 = (_Float16*)(ws + off);  off += (size_t)4*F2_DIM*(H_DIM*8)*2;
  _Float16* wk1 = (_Float16*)(ws + off);  off += (size_t)4*H_DIM*(F2_DIM*8)*2;
  // total ~470 MB

  hipMemsetAsync(out, 0, (size_t)out_size*sizeof(float), stream);
  if (ws_size < off) return;   // ws too small: leave zeroed output (clean validation
                               // failure) instead of corrupting memory. Constant per
                               // call -> graph-capture-safe.
  hipMemsetAsync(cnt, 0, 256, stream);
  hipMemsetAsync(zstats, 0, (size_t)4*CAP*2*4, stream);

  k_gate<<<dim3(T_TOK/4), 256, 0, stream>>>(x, gateW, cnt, tok, wgt, xst);
  k_transform<<<dim3(2560), 256, 0, stream>>>(mlpW1, mlpW2, kanW0, kanW1,
                                              wt1, wt2, wk0, wk1);
  k_pair1<<<dim3(3072), 256, 0, stream>>>(x, wt1, mlpB1, wk0, kanB0,
      xst, lng0, lnb0, cnt, tok, wgt, h1, zbuf, zstats);
  k_pair2<<<dim3(2048), 256, 0, stream>>>(h1, wt2, mlpB2, zbuf, wk1, kanB1,
      zstats, lng1, lnb1, cnt, tok, wgt, out);
}